// Round 3
// baseline (194.946 us; speedup 1.0000x reference)
//
#include <hip/hip_runtime.h>
#include <cmath>

#define NPTS 4096
#define NPOINT 204   // int(4096 * 0.05)
#define NPCT 5
#define MAXNS 409    // int(4096 * 0.10)
#define FPS_T 256
#define NGROUP 408   // B * NPOINT
#define NPART (NGROUP * NPCT)
#define MAXSLOT 7    // ceil(409/64)

// fused-launch geometry: 512 blocks = 2 blocks/CU x 256 CUs, all co-resident.
// Blocks 0,1: FPS. Blocks 2..511: 510 workers, 4 static tasks each (R1-proven
// layout). The LAST worker to finish performs the final reduction in-kernel
// (tournament on g_done) -> single kernel node, no memset / reduce nodes.
#define NBLOCKS 512
#define NWORKER 510
#define NROUND  4    // 510 * 4 = 2040 = NPART

// shared-memory union layout (bytes)
#define SMEM_BYTES 65600          // fps: float4 pts[4096] (65536) + keys (64)
#define KEYS_OFF   65536
#define WRES_OFF   6544           // grp: gpts float4[409] = 6544
#define WTOT_OFF   20880          //      wres float2[4][7][64] = 14336
#define SPART_OFF  20896
#define SCTL_OFF   20912          // 2 ints: {qi / finisher-flag}

typedef unsigned long long u64;
typedef float f32x2 __attribute__((ext_vector_type(2)));

struct LossParams {
    int   nsample[NPCT];
    float r2[NPCT];
    float wscale[NPCT];   // (p*100)^2 / (B*NPOINT*NPCT)
    float expect_len;
};

// ---------------------------------------------------------------------------
// Persistent device state (replaces workspace sentinel + memset node).
// g_fps[i] == 0  -> not yet produced (static zero-init: first-run safe)
// g_fps[i] == ~k -> FPS produced index k (always negative since k >= 0)
// The finishing worker resets state at the END of each execution; kernel
// boundaries on the stream order that reset before the next replay's reads.
// ---------------------------------------------------------------------------
__device__ int g_fps[NGROUP];
__device__ int g_done;

// ---------------- DPP wave64 reductions (R1-proven, DPP-fused max/min) -----
template <int CTRL>
__device__ __forceinline__ int dpp_imax(int v) {
    int t = __builtin_amdgcn_update_dpp(0, v, CTRL, 0xf, 0xf, true);
    return v > t ? v : t;
}
template <int CTRL>
__device__ __forceinline__ int dpp_imin(int v) {
    int t = __builtin_amdgcn_update_dpp(0x7fffffff, v, CTRL, 0xf, 0xf, false);
    return v < t ? v : t;
}
__device__ __forceinline__ int wave_max_i(int v) {
    v = dpp_imax<0x111>(v); v = dpp_imax<0x112>(v);
    v = dpp_imax<0x114>(v); v = dpp_imax<0x118>(v);
    v = dpp_imax<0x142>(v); v = dpp_imax<0x143>(v);
    return __builtin_amdgcn_readlane(v, 63);
}
__device__ __forceinline__ int wave_min_i(int v) {
    v = dpp_imin<0x111>(v); v = dpp_imin<0x112>(v);
    v = dpp_imin<0x114>(v); v = dpp_imin<0x118>(v);
    v = dpp_imin<0x142>(v); v = dpp_imin<0x143>(v);
    return __builtin_amdgcn_readlane(v, 63);
}
template <int CTRL>
__device__ __forceinline__ u64 dpp_u64max(u64 v) {
    int lo = (int)(unsigned)v;
    int hi = (int)(unsigned)(v >> 32);
    unsigned slo = (unsigned)__builtin_amdgcn_update_dpp(0, lo, CTRL, 0xf, 0xf, true);
    unsigned shi = (unsigned)__builtin_amdgcn_update_dpp(0, hi, CTRL, 0xf, 0xf, true);
    u64 o = ((u64)shi << 32) | slo;
    return v > o ? v : o;
}

// ---------------------------------------------------------------------------
// FPS role — distance math and reduce plumbing IDENTICAL to the 135.7 µs R1
// version. ONE change: the per-lane 16-element argmax scan (16-deep dependent
// compare-select chain) is now a 4-level balanced tree. Tie rule preserved:
// pairs are index-ordered at every level and ">=" keeps the left (smaller
// index) operand == keep-earliest-max of the original scan.
// ---------------------------------------------------------------------------
__device__ void fps_role(const float* __restrict__ pcd, char* smem) {
#pragma clang fp contract(off)
    __builtin_amdgcn_s_setprio(3);
    float4* pts = reinterpret_cast<float4*>(smem);          // 64 KB
    u64 (*keys)[4] = reinterpret_cast<u64 (*)[4]>(smem + KEYS_OFF);

    const int b = blockIdx.x;
    const int t = threadIdx.x;
    const int wave = t >> 6, lane = t & 63;
    const float* base = pcd + (size_t)b * NPTS * 3;

    f32x2 X[8], Y[8], Z[8], D[8];
    #pragma unroll
    for (int q = 0; q < 8; ++q) {
        int n0 = (2 * q) * FPS_T + t;
        int n1 = (2 * q + 1) * FPS_T + t;
        float x0 = base[3 * n0 + 0], y0 = base[3 * n0 + 1], z0 = base[3 * n0 + 2];
        float x1 = base[3 * n1 + 0], y1 = base[3 * n1 + 1], z1 = base[3 * n1 + 2];
        pts[n0] = make_float4(x0, y0, z0, 0.0f);
        pts[n1] = make_float4(x1, y1, z1, 0.0f);
        X[q] = (f32x2){x0, x1};
        Y[q] = (f32x2){y0, y1};
        Z[q] = (f32x2){z0, z1};
        D[q] = (f32x2){1e10f, 1e10f};
    }
    int* out = g_fps + b * NPOINT;
    if (t == 0)
        __hip_atomic_store(&out[0], ~0, __ATOMIC_RELAXED, __HIP_MEMORY_SCOPE_AGENT);
    __syncthreads();

    float4 c = pts[0];
    for (int it = 1; it < NPOINT; ++it) {
        f32x2 cxx = (f32x2){c.x, c.x};
        f32x2 cyy = (f32x2){c.y, c.y};
        f32x2 czz = (f32x2){c.z, c.z};
        int tb[8], ti[8];
        #pragma unroll
        for (int q = 0; q < 8; ++q) {
            f32x2 dx = X[q] - cxx, dy = Y[q] - cyy, dz = Z[q] - czz;
            f32x2 d  = (dx * dx + dy * dy) + dz * dz;
            f32x2 dd = D[q];
            float d0 = fminf(dd.x, d.x);
            float d1 = fminf(dd.y, d.y);
            D[q] = (f32x2){d0, d1};
            int b0 = __float_as_int(d0);     // d >= 0: int cmp == float cmp
            int b1 = __float_as_int(d1);
            bool c0 = b0 >= b1;              // tie -> keep smaller index
            tb[q] = c0 ? b0 : b1;
            ti[q] = c0 ? (2 * q) * FPS_T + t : (2 * q + 1) * FPS_T + t;
        }
        // balanced tree, depth 3 more levels; index order preserved per pair
        #pragma unroll
        for (int st = 1; st < 8; st <<= 1) {
            #pragma unroll
            for (int q = 0; q < 8; q += 2 * st) {
                bool cc = tb[q] >= tb[q + st];
                tb[q] = cc ? tb[q] : tb[q + st];
                ti[q] = cc ? ti[q] : ti[q + st];
            }
        }
        int bb = tb[0], bi = ti[0];

        int wmax = wave_max_i(bb);
        int cand = (bb == wmax) ? bi : 0x7fffffff;
        int widx = wave_min_i(cand);
        if (lane == 0)
            keys[it & 1][wave] =
                ((u64)(unsigned)wmax << 32) | (unsigned)~(unsigned)widx;
        __syncthreads();
        u64 kv = keys[it & 1][lane & 3];
        kv = dpp_u64max<0x111>(kv);
        kv = dpp_u64max<0x112>(kv);
        unsigned lo3 = (unsigned)__builtin_amdgcn_readlane((int)(unsigned)kv, 3);
        int last = (int)~lo3;
        c = pts[last];
        if (t == 0)
            __hip_atomic_store(&out[it], ~last, __ATOMIC_RELAXED, __HIP_MEMORY_SCOPE_AGENT);
    }
}

// ---- Phase B worker: K i-slots/lane, j streamed over this wave's quarter ---
template <int K>
__device__ __forceinline__ void phaseB(const float4* __restrict__ gpts,
                                       float2 (*wres)[64],   // [MAXSLOT][64], this wave's slab
                                       int j0, int j1, int lane, int cntB) {
    float4 pi[K];
    float m1[K], m2[K];
    #pragma unroll
    for (int s = 0; s < K; ++s) {
        int idx = s * 64 + lane;
        pi[s] = gpts[idx < cntB ? idx : 0];   // dummy lanes skipped at merge
        m1[s] = 1e30f; m2[s] = 1e30f;
    }
    #pragma unroll 2
    for (int j = j0; j < j1; ++j) {
        float4 a = gpts[j];                   // wave-uniform broadcast read
        #pragma unroll
        for (int s = 0; s < K; ++s) {
            float tt = pi[s].x * a.x;
            tt = fmaf(pi[s].y, a.y, tt);
            tt = fmaf(pi[s].z, a.z, tt);
            float h = fmaf(-2.0f, tt, a.w);   // |a|^2 - 2<pi,a>
            m2[s] = __builtin_amdgcn_fmed3f(m1[s], m2[s], h);
            m1[s] = fminf(m1[s], h);
        }
    }
    #pragma unroll
    for (int s = 0; s < K; ++s) wres[s][lane] = (float2){m1[s], m2[s]};
}

// ---------------------------------------------------------------------------
// Worker role: R1-proven static assignment, tau = w + round*510 (ascending m
// -> tasks unlock progressively while FPS runs). Task math IDENTICAL.
// After the 4 rounds, tournament on g_done: the 510th finisher reduces
// partials (same order as the old reduce_kernel -> bit-identical), writes
// out, and resets persistent state for the next replay.
// ---------------------------------------------------------------------------
__device__ void worker_role(const float* __restrict__ pcd,
                            float* __restrict__ partials,
                            float* __restrict__ out,
                            const LossParams& P, char* smem) {
    float4* gpts = reinterpret_cast<float4*>(smem);
    auto wres    = reinterpret_cast<float2 (*)[MAXSLOT][64]>(smem + WRES_OFF);
    int*   s_wtot = reinterpret_cast<int*>(smem + WTOT_OFF);
    float* s_part = reinterpret_cast<float*>(smem + SPART_OFF);
    int*   s_ctl  = reinterpret_cast<int*>(smem + SCTL_OFF);

    const int w = blockIdx.x - 2;
    const int t = threadIdx.x;
    const int wave = t >> 6, lane = t & 63;

    for (int round = 0; round < NROUND; ++round) {
        const int tau  = w + round * NWORKER;        // 0 .. NPART-1, each once
        const int m_   = tau / 10;                   // group row (unlock order)
        const int rem  = tau - m_ * 10;
        const int b    = rem / 5;
        const int pidx = rem - b * 5;

        const int   ns = P.nsample[pidx];
        const float r2 = P.r2[pidx];
        const float* base = pcd + (size_t)b * NPTS * 3;

        if (t == 0) {
            int v;
            while ((v = __hip_atomic_load(&g_fps[b * NPOINT + m_],
                                          __ATOMIC_RELAXED,
                                          __HIP_MEMORY_SCOPE_AGENT)) >= 0)
                __builtin_amdgcn_s_sleep(16);
            s_ctl[0] = ~v;
        }
        __syncthreads();
        const int qi = s_ctl[0];
        float qx = base[3 * qi + 0], qy = base[3 * qi + 1], qz = base[3 * qi + 2];

        // ---- Phase A pass 1: ballot the wave's 16 sub-chunks of 64 points ----
        unsigned long long msk[16];
        int lbase[16];
        int run = 0;
        #pragma unroll 4
        for (int s = 0; s < 16; ++s) {
            int n = wave * 1024 + s * 64 + lane;
            float x = base[3 * n + 0];
            float y = base[3 * n + 1];
            float z = base[3 * n + 2];
            float d2;
            {
#pragma clang fp contract(off)
                float dx = qx - x, dy = qy - y, dz = qz - z;
                float aa = dx * dx, bb2 = dy * dy, cc = dz * dz;
                d2 = (aa + bb2) + cc;
            }
            msk[s] = __ballot(d2 < r2);        // strict <, matches reference
            lbase[s] = run;
            run += __popcll(msk[s]);
        }
        if (lane == 0) s_wtot[wave] = run;
        __syncthreads();
        int w0 = s_wtot[0], w1 = s_wtot[1], w2 = s_wtot[2], w3 = s_wtot[3];
        int Bw = (wave > 0 ? w0 : 0) + (wave > 1 ? w1 : 0) + (wave > 2 ? w2 : 0);
        int cnt  = w0 + w1 + w2 + w3;
        int cntB = cnt < ns ? cnt : ns;
        const int npad = ns - cntB;

        // ---- Phase A pass 2: ordered compaction into LDS, w = |p|^2 ----
        #pragma unroll 4
        for (int s = 0; s < 16; ++s) {
            int gb = Bw + lbase[s];            // wave-uniform
            if (gb >= ns) break;
            unsigned long long mk = msk[s];
            bool in = (mk >> lane) & 1ull;
            int pos = gb + __popcll(mk & ((1ull << lane) - 1ull));
            if (in && pos < ns) {
                int n = wave * 1024 + s * 64 + lane;
                float x = base[3 * n], y = base[3 * n + 1], z = base[3 * n + 2];
                float sq = fmaf(x, x, fmaf(y, y, z * z));
                gpts[pos] = make_float4(x, y, z, sq);
            }
        }
        __syncthreads();

        // ---- Phase B: each wave streams its quarter of j ----
        const int quarter = (cntB + 3) >> 2;
        const int j0 = wave * quarter;
        const int j1 = (j0 + quarter) < cntB ? (j0 + quarter) : cntB;
        const int nslot = (cntB + 63) >> 6;    // 1..7
        switch (nslot) {
            case 1: phaseB<1>(gpts, wres[wave], j0, j1, lane, cntB); break;
            case 2: phaseB<2>(gpts, wres[wave], j0, j1, lane, cntB); break;
            case 3: phaseB<3>(gpts, wres[wave], j0, j1, lane, cntB); break;
            case 4: phaseB<4>(gpts, wres[wave], j0, j1, lane, cntB); break;
            case 5: phaseB<5>(gpts, wres[wave], j0, j1, lane, cntB); break;
            case 6: phaseB<6>(gpts, wres[wave], j0, j1, lane, cntB); break;
            default: phaseB<7>(gpts, wres[wave], j0, j1, lane, cntB); break;
        }
        __syncthreads();

        // ---- Merge 4 waves' min2 pairs per i; then sum sqrt ----
        float sum = 0.0f;
        for (int it = t; it < nslot * 64; it += 256) {
            int i = it;
            if (i < cntB) {
                int s = it >> 6, l = it & 63;
                float2 a  = wres[0][s][l];
                float2 bq = wres[1][s][l];
                float2 cq = wres[2][s][l];
                float2 dq = wres[3][s][l];
                float e1 = fminf(a.x, bq.x), e2 = fminf(fmaxf(a.x, bq.x), fminf(a.y, bq.y));
                float f1 = fminf(cq.x, dq.x), f2 = fminf(fmaxf(cq.x, dq.x), fminf(cq.y, dq.y));
                float m2v = fminf(fmaxf(e1, f1), fminf(e2, f2));
                float sq = gpts[i].w;
                float d2 = fmaxf(sq + m2v, 0.0f);
                if (!(i == 0 && npad > 0)) sum += sqrtf(d2);
            }
        }
        #pragma unroll
        for (int off = 32; off; off >>= 1) sum += __shfl_down(sum, off);
        if (lane == 0) s_part[wave] = sum;
        __syncthreads();
        if (t == 0) {
            float tot = s_part[0] + s_part[1] + s_part[2] + s_part[3] + 0.1f * (float)ns;
            float u  = tot / (float)ns;
            float du = u - P.expect_len;
            partials[tau] = du * du / (P.expect_len + 0.1f) * P.wscale[pidx];
        }
    }

    // ---- finisher tournament: last of the 510 workers reduces + resets ----
    if (t == 0) {
        int old = __hip_atomic_fetch_add(&g_done, 1, __ATOMIC_ACQ_REL,
                                         __HIP_MEMORY_SCOPE_AGENT);
        s_ctl[0] = old;
    }
    __syncthreads();
    if (s_ctl[0] == NWORKER - 1) {
        // every thread performs an acquire before loading partials
        (void)__hip_atomic_load(&g_done, __ATOMIC_ACQUIRE, __HIP_MEMORY_SCOPE_AGENT);
        float s = 0.0f;
        for (int i = t; i < NPART; i += 256) s += partials[i];
        #pragma unroll
        for (int off = 32; off; off >>= 1) s += __shfl_down(s, off);
        if (lane == 0) s_part[wave] = s;
        __syncthreads();
        if (t == 0) out[0] = s_part[0] + s_part[1] + s_part[2] + s_part[3];
        // reset persistent state for the next graph replay
        for (int i = t; i < NGROUP; i += 256) g_fps[i] = 0;
        if (t == 0) g_done = 0;
    }
}

// ---------------------------------------------------------------------------
// Fused kernel: 512 blocks @ 66 KB LDS -> 2 blocks/CU x 256 CU, co-resident.
// No circular wait: FPS depends on nobody; workers depend only on FPS; the
// finishing worker depends only on the other workers.
// ---------------------------------------------------------------------------
__global__ __launch_bounds__(256, 2) void fused_kernel(const float* __restrict__ pcd,
                                                       float* __restrict__ partials,
                                                       float* __restrict__ out,
                                                       LossParams P) {
    __shared__ __align__(16) char smem[SMEM_BYTES];
    if (blockIdx.x < 2) {
        fps_role(pcd, smem);
    } else {
        worker_role(pcd, partials, out, P, smem);
    }
}

extern "C" void kernel_launch(void* const* d_in, const int* in_sizes, int n_in,
                              void* d_out, int out_size, void* d_ws, size_t ws_size,
                              hipStream_t stream) {
    const float* pcd = (const float*)d_in[0];
    float* out = (float*)d_out;
    float* partials = (float*)d_ws;           // [0, NPART) floats

    LossParams P;
    const double ps[NPCT] = {0.02, 0.04, 0.06, 0.08, 0.10};
    for (int i = 0; i < NPCT; ++i) {
        P.nsample[i] = (int)(NPTS * ps[i]);
        double r = std::sqrt(ps[i] * 1.0);
        P.r2[i] = (float)(r * r);
        double w = (ps[i] * 100.0) * (ps[i] * 100.0);
        P.wscale[i] = (float)(w / (double)(2 * NPOINT * NPCT));
    }
    P.expect_len = (float)std::sqrt(3.14159265358979323846 / (double)NPTS);

    fused_kernel<<<dim3(NBLOCKS), dim3(256), 0, stream>>>(pcd, partials, out, P);
}

// Round 4
// 193.606 us; speedup vs baseline: 1.0069x; 1.0069x over previous
//
#include <hip/hip_runtime.h>
#include <cmath>

#define NPTS 4096
#define NPOINT 204   // int(4096 * 0.05)
#define NPCT 5
#define MAXNS 409    // int(4096 * 0.10)
#define FPS_T 256
#define NGROUP 408   // B * NPOINT
#define NPART (NGROUP * NPCT)
#define MAXSLOT 7    // ceil(409/64)

// fused-launch geometry: 512 blocks = 2 blocks/CU x 256 CUs, all co-resident.
// Blocks 0,1: FPS. Blocks 256,257: EXIT IMMEDIATELY — under round-robin
// placement (block i -> XCD i%8, CU (i/8)%32, occupant i/256) they are the
// second occupants of the FPS CUs; exiting them leaves FPS uncontended.
// Workers: the remaining 508 blocks. 508*4 = 2032 static tasks + 8 prologue
// tasks (m=0, unlocked instantly) on workers 0..7 -> all 2040 covered.
#define NBLOCKS 512
#define NWORKER 508
#define NROUND  4

// shared-memory union layout (bytes)
#define SMEM_BYTES 65600          // fps: float4 pts[4096] (65536) + keys (64)
#define KEYS_OFF   65536
#define WRES_OFF   6544           // grp: gpts float4[409] = 6544
#define WTOT_OFF   20880          //      wres float2[4][7][64] = 14336
#define SPART_OFF  20896
#define SCTL_OFF   20912          // 2 ints: {qi / finisher-flag}

typedef unsigned long long u64;
typedef float f32x2 __attribute__((ext_vector_type(2)));

struct LossParams {
    int   nsample[NPCT];
    float r2[NPCT];
    float wscale[NPCT];   // (p*100)^2 / (B*NPOINT*NPCT)
    float expect_len;
};

// ---------------------------------------------------------------------------
// Persistent device state (replaces workspace sentinel + memset node).
// g_fps[i] == 0  -> not yet produced (static zero-init: first-run safe)
// g_fps[i] == ~k -> FPS produced index k (always negative since k >= 0)
// The finishing worker resets state at the END of each execution; kernel
// boundaries on the stream order that reset before the next replay's reads.
// ---------------------------------------------------------------------------
__device__ int g_fps[NGROUP];
__device__ int g_done;

// ---------------- DPP wave64 reductions (R1-proven, DPP-fused max/min) -----
template <int CTRL>
__device__ __forceinline__ int dpp_imax(int v) {
    int t = __builtin_amdgcn_update_dpp(0, v, CTRL, 0xf, 0xf, true);
    return v > t ? v : t;
}
template <int CTRL>
__device__ __forceinline__ int dpp_imin(int v) {
    int t = __builtin_amdgcn_update_dpp(0x7fffffff, v, CTRL, 0xf, 0xf, false);
    return v < t ? v : t;
}
__device__ __forceinline__ int wave_max_i(int v) {
    v = dpp_imax<0x111>(v); v = dpp_imax<0x112>(v);
    v = dpp_imax<0x114>(v); v = dpp_imax<0x118>(v);
    v = dpp_imax<0x142>(v); v = dpp_imax<0x143>(v);
    return __builtin_amdgcn_readlane(v, 63);
}
__device__ __forceinline__ int wave_min_i(int v) {
    v = dpp_imin<0x111>(v); v = dpp_imin<0x112>(v);
    v = dpp_imin<0x114>(v); v = dpp_imin<0x118>(v);
    v = dpp_imin<0x142>(v); v = dpp_imin<0x143>(v);
    return __builtin_amdgcn_readlane(v, 63);
}
template <int CTRL>
__device__ __forceinline__ u64 dpp_u64max(u64 v) {
    int lo = (int)(unsigned)v;
    int hi = (int)(unsigned)(v >> 32);
    unsigned slo = (unsigned)__builtin_amdgcn_update_dpp(0, lo, CTRL, 0xf, 0xf, true);
    unsigned shi = (unsigned)__builtin_amdgcn_update_dpp(0, hi, CTRL, 0xf, 0xf, true);
    u64 o = ((u64)shi << 32) | slo;
    return v > o ? v : o;
}

// ---------------------------------------------------------------------------
// FPS role — EXACT R1-proven body (scan argmax, dual DPP max/min chains,
// keys ping-pong). Only the publish encoding (~idx into g_fps) differs.
// ---------------------------------------------------------------------------
__device__ void fps_role(const float* __restrict__ pcd, char* smem) {
#pragma clang fp contract(off)
    __builtin_amdgcn_s_setprio(3);
    float4* pts = reinterpret_cast<float4*>(smem);          // 64 KB
    u64 (*keys)[4] = reinterpret_cast<u64 (*)[4]>(smem + KEYS_OFF);

    const int b = blockIdx.x;
    const int t = threadIdx.x;
    const int wave = t >> 6, lane = t & 63;
    const float* base = pcd + (size_t)b * NPTS * 3;

    f32x2 X[8], Y[8], Z[8], D[8];
    #pragma unroll
    for (int q = 0; q < 8; ++q) {
        int n0 = (2 * q) * FPS_T + t;
        int n1 = (2 * q + 1) * FPS_T + t;
        float x0 = base[3 * n0 + 0], y0 = base[3 * n0 + 1], z0 = base[3 * n0 + 2];
        float x1 = base[3 * n1 + 0], y1 = base[3 * n1 + 1], z1 = base[3 * n1 + 2];
        pts[n0] = make_float4(x0, y0, z0, 0.0f);
        pts[n1] = make_float4(x1, y1, z1, 0.0f);
        X[q] = (f32x2){x0, x1};
        Y[q] = (f32x2){y0, y1};
        Z[q] = (f32x2){z0, z1};
        D[q] = (f32x2){1e10f, 1e10f};
    }
    int* out = g_fps + b * NPOINT;
    if (t == 0)
        __hip_atomic_store(&out[0], ~0, __ATOMIC_RELAXED, __HIP_MEMORY_SCOPE_AGENT);
    __syncthreads();

    float4 c = pts[0];
    for (int it = 1; it < NPOINT; ++it) {
        f32x2 cxx = (f32x2){c.x, c.x};
        f32x2 cyy = (f32x2){c.y, c.y};
        f32x2 czz = (f32x2){c.z, c.z};
        int bb = -1, bi = 0;
        #pragma unroll
        for (int q = 0; q < 8; ++q) {
            f32x2 dx = X[q] - cxx, dy = Y[q] - cyy, dz = Z[q] - czz;
            f32x2 d  = (dx * dx + dy * dy) + dz * dz;
            f32x2 dd = D[q];
            float d0 = fminf(dd.x, d.x);
            float d1 = fminf(dd.y, d.y);
            D[q] = (f32x2){d0, d1};
            int b0 = __float_as_int(d0);
            int b1 = __float_as_int(d1);
            if (b0 > bb) { bb = b0; bi = (2 * q) * FPS_T + t; }
            if (b1 > bb) { bb = b1; bi = (2 * q + 1) * FPS_T + t; }
        }
        int wmax = wave_max_i(bb);
        int cand = (bb == wmax) ? bi : 0x7fffffff;
        int widx = wave_min_i(cand);
        if (lane == 0)
            keys[it & 1][wave] =
                ((u64)(unsigned)wmax << 32) | (unsigned)~(unsigned)widx;
        __syncthreads();
        u64 kv = keys[it & 1][lane & 3];
        kv = dpp_u64max<0x111>(kv);
        kv = dpp_u64max<0x112>(kv);
        unsigned lo3 = (unsigned)__builtin_amdgcn_readlane((int)(unsigned)kv, 3);
        int last = (int)~lo3;
        c = pts[last];
        if (t == 0)
            __hip_atomic_store(&out[it], ~last, __ATOMIC_RELAXED, __HIP_MEMORY_SCOPE_AGENT);
    }
}

// ---- Phase B worker: K i-slots/lane, j streamed over this wave's quarter ---
template <int K>
__device__ __forceinline__ void phaseB(const float4* __restrict__ gpts,
                                       float2 (*wres)[64],   // [MAXSLOT][64], this wave's slab
                                       int j0, int j1, int lane, int cntB) {
    float4 pi[K];
    float m1[K], m2[K];
    #pragma unroll
    for (int s = 0; s < K; ++s) {
        int idx = s * 64 + lane;
        pi[s] = gpts[idx < cntB ? idx : 0];   // dummy lanes skipped at merge
        m1[s] = 1e30f; m2[s] = 1e30f;
    }
    #pragma unroll 2
    for (int j = j0; j < j1; ++j) {
        float4 a = gpts[j];                   // wave-uniform broadcast read
        #pragma unroll
        for (int s = 0; s < K; ++s) {
            float tt = pi[s].x * a.x;
            tt = fmaf(pi[s].y, a.y, tt);
            tt = fmaf(pi[s].z, a.z, tt);
            float h = fmaf(-2.0f, tt, a.w);   // |a|^2 - 2<pi,a>
            m2[s] = __builtin_amdgcn_fmed3f(m1[s], m2[s], h);
            m1[s] = fminf(m1[s], h);
        }
    }
    #pragma unroll
    for (int s = 0; s < K; ++s) wres[s][lane] = (float2){m1[s], m2[s]};
}

// ---------------------------------------------------------------------------
// Worker role: static assignment over 508 workers. Worker w (0..507) runs
// tau = 8 + w + round*508 for round 0..3; workers 0..7 additionally run the
// prologue task tau = w (m=0, available immediately). Each worker's tau
// sequence is ascending in m -> tasks unlock progressively while FPS runs.
// Task math IDENTICAL to the proven worker; partials[tau] mapping unchanged
// -> bit-identical final sum. After all tasks, tournament on g_done: the
// 508th finisher reduces partials (same order as the old reduce_kernel),
// writes out, and resets persistent state for the next replay.
// ---------------------------------------------------------------------------
__device__ void worker_role(const float* __restrict__ pcd,
                            float* __restrict__ partials,
                            float* __restrict__ out,
                            const LossParams& P, char* smem, int w) {
    float4* gpts = reinterpret_cast<float4*>(smem);
    auto wres    = reinterpret_cast<float2 (*)[MAXSLOT][64]>(smem + WRES_OFF);
    int*   s_wtot = reinterpret_cast<int*>(smem + WTOT_OFF);
    float* s_part = reinterpret_cast<float*>(smem + SPART_OFF);
    int*   s_ctl  = reinterpret_cast<int*>(smem + SCTL_OFF);

    const int t = threadIdx.x;
    const int wave = t >> 6, lane = t & 63;

    for (int round = (w < 8 ? -1 : 0); round < NROUND; ++round) {
        const int tau  = (round < 0) ? w : 8 + w + round * NWORKER;  // covers 0..2039
        const int m_   = tau / 10;                   // group row (unlock order)
        const int rem  = tau - m_ * 10;
        const int b    = rem / 5;
        const int pidx = rem - b * 5;

        const int   ns = P.nsample[pidx];
        const float r2 = P.r2[pidx];
        const float* base = pcd + (size_t)b * NPTS * 3;

        if (t == 0) {
            int v;
            while ((v = __hip_atomic_load(&g_fps[b * NPOINT + m_],
                                          __ATOMIC_RELAXED,
                                          __HIP_MEMORY_SCOPE_AGENT)) >= 0)
                __builtin_amdgcn_s_sleep(16);
            s_ctl[0] = ~v;
        }
        __syncthreads();
        const int qi = s_ctl[0];
        float qx = base[3 * qi + 0], qy = base[3 * qi + 1], qz = base[3 * qi + 2];

        // ---- Phase A pass 1: ballot the wave's 16 sub-chunks of 64 points ----
        unsigned long long msk[16];
        int lbase[16];
        int run = 0;
        #pragma unroll 4
        for (int s = 0; s < 16; ++s) {
            int n = wave * 1024 + s * 64 + lane;
            float x = base[3 * n + 0];
            float y = base[3 * n + 1];
            float z = base[3 * n + 2];
            float d2;
            {
#pragma clang fp contract(off)
                float dx = qx - x, dy = qy - y, dz = qz - z;
                float aa = dx * dx, bb2 = dy * dy, cc = dz * dz;
                d2 = (aa + bb2) + cc;
            }
            msk[s] = __ballot(d2 < r2);        // strict <, matches reference
            lbase[s] = run;
            run += __popcll(msk[s]);
        }
        if (lane == 0) s_wtot[wave] = run;
        __syncthreads();
        int w0 = s_wtot[0], w1 = s_wtot[1], w2 = s_wtot[2], w3 = s_wtot[3];
        int Bw = (wave > 0 ? w0 : 0) + (wave > 1 ? w1 : 0) + (wave > 2 ? w2 : 0);
        int cnt  = w0 + w1 + w2 + w3;
        int cntB = cnt < ns ? cnt : ns;
        const int npad = ns - cntB;

        // ---- Phase A pass 2: ordered compaction into LDS, w = |p|^2 ----
        #pragma unroll 4
        for (int s = 0; s < 16; ++s) {
            int gb = Bw + lbase[s];            // wave-uniform
            if (gb >= ns) break;
            unsigned long long mk = msk[s];
            bool in = (mk >> lane) & 1ull;
            int pos = gb + __popcll(mk & ((1ull << lane) - 1ull));
            if (in && pos < ns) {
                int n = wave * 1024 + s * 64 + lane;
                float x = base[3 * n], y = base[3 * n + 1], z = base[3 * n + 2];
                float sq = fmaf(x, x, fmaf(y, y, z * z));
                gpts[pos] = make_float4(x, y, z, sq);
            }
        }
        __syncthreads();

        // ---- Phase B: each wave streams its quarter of j ----
        const int quarter = (cntB + 3) >> 2;
        const int j0 = wave * quarter;
        const int j1 = (j0 + quarter) < cntB ? (j0 + quarter) : cntB;
        const int nslot = (cntB + 63) >> 6;    // 1..7
        switch (nslot) {
            case 1: phaseB<1>(gpts, wres[wave], j0, j1, lane, cntB); break;
            case 2: phaseB<2>(gpts, wres[wave], j0, j1, lane, cntB); break;
            case 3: phaseB<3>(gpts, wres[wave], j0, j1, lane, cntB); break;
            case 4: phaseB<4>(gpts, wres[wave], j0, j1, lane, cntB); break;
            case 5: phaseB<5>(gpts, wres[wave], j0, j1, lane, cntB); break;
            case 6: phaseB<6>(gpts, wres[wave], j0, j1, lane, cntB); break;
            default: phaseB<7>(gpts, wres[wave], j0, j1, lane, cntB); break;
        }
        __syncthreads();

        // ---- Merge 4 waves' min2 pairs per i; then sum sqrt ----
        float sum = 0.0f;
        for (int it = t; it < nslot * 64; it += 256) {
            int i = it;
            if (i < cntB) {
                int s = it >> 6, l = it & 63;
                float2 a  = wres[0][s][l];
                float2 bq = wres[1][s][l];
                float2 cq = wres[2][s][l];
                float2 dq = wres[3][s][l];
                float e1 = fminf(a.x, bq.x), e2 = fminf(fmaxf(a.x, bq.x), fminf(a.y, bq.y));
                float f1 = fminf(cq.x, dq.x), f2 = fminf(fmaxf(cq.x, dq.x), fminf(cq.y, dq.y));
                float m2v = fminf(fmaxf(e1, f1), fminf(e2, f2));
                float sq = gpts[i].w;
                float d2 = fmaxf(sq + m2v, 0.0f);
                if (!(i == 0 && npad > 0)) sum += sqrtf(d2);
            }
        }
        #pragma unroll
        for (int off = 32; off; off >>= 1) sum += __shfl_down(sum, off);
        if (lane == 0) s_part[wave] = sum;
        __syncthreads();
        if (t == 0) {
            float tot = s_part[0] + s_part[1] + s_part[2] + s_part[3] + 0.1f * (float)ns;
            float u  = tot / (float)ns;
            float du = u - P.expect_len;
            partials[tau] = du * du / (P.expect_len + 0.1f) * P.wscale[pidx];
        }
        __syncthreads();   // protect s_ctl/s_part before next round's writes
    }

    // ---- finisher tournament: last of the 508 workers reduces + resets ----
    if (t == 0) {
        int old = __hip_atomic_fetch_add(&g_done, 1, __ATOMIC_ACQ_REL,
                                         __HIP_MEMORY_SCOPE_AGENT);
        s_ctl[0] = old;
    }
    __syncthreads();
    if (s_ctl[0] == NWORKER - 1) {
        // every thread performs an acquire before loading partials
        (void)__hip_atomic_load(&g_done, __ATOMIC_ACQUIRE, __HIP_MEMORY_SCOPE_AGENT);
        float s = 0.0f;
        for (int i = t; i < NPART; i += 256) s += partials[i];
        #pragma unroll
        for (int off = 32; off; off >>= 1) s += __shfl_down(s, off);
        if (lane == 0) s_part[wave] = s;
        __syncthreads();
        if (t == 0) out[0] = s_part[0] + s_part[1] + s_part[2] + s_part[3];
        // reset persistent state for the next graph replay
        for (int i = t; i < NGROUP; i += 256) g_fps[i] = 0;
        if (t == 0) g_done = 0;
    }
}

// ---------------------------------------------------------------------------
// Fused kernel: 512 blocks @ 66 KB LDS -> 2 blocks/CU x 256 CU, co-resident.
// No circular wait: FPS depends on nobody; workers depend only on FPS; the
// finishing worker depends only on the other workers. Blocks 256/257 exit
// instantly (they pair with the FPS CUs under round-robin placement).
// ---------------------------------------------------------------------------
__global__ __launch_bounds__(256, 2) void fused_kernel(const float* __restrict__ pcd,
                                                       float* __restrict__ partials,
                                                       float* __restrict__ out,
                                                       LossParams P) {
    __shared__ __align__(16) char smem[SMEM_BYTES];
    const int bid = blockIdx.x;
    if (bid == 256 || bid == 257) return;
    if (bid < 2) {
        fps_role(pcd, smem);
    } else {
        const int w = (bid < 256) ? bid - 2 : bid - 4;   // 0..507
        worker_role(pcd, partials, out, P, smem, w);
    }
}

extern "C" void kernel_launch(void* const* d_in, const int* in_sizes, int n_in,
                              void* d_out, int out_size, void* d_ws, size_t ws_size,
                              hipStream_t stream) {
    const float* pcd = (const float*)d_in[0];
    float* out = (float*)d_out;
    float* partials = (float*)d_ws;           // [0, NPART) floats

    LossParams P;
    const double ps[NPCT] = {0.02, 0.04, 0.06, 0.08, 0.10};
    for (int i = 0; i < NPCT; ++i) {
        P.nsample[i] = (int)(NPTS * ps[i]);
        double r = std::sqrt(ps[i] * 1.0);
        P.r2[i] = (float)(r * r);
        double w = (ps[i] * 100.0) * (ps[i] * 100.0);
        P.wscale[i] = (float)(w / (double)(2 * NPOINT * NPCT));
    }
    P.expect_len = (float)std::sqrt(3.14159265358979323846 / (double)NPTS);

    fused_kernel<<<dim3(NBLOCKS), dim3(256), 0, stream>>>(pcd, partials, out, P);
}

// Round 5
// 187.220 us; speedup vs baseline: 1.0413x; 1.0341x over previous
//
#include <hip/hip_runtime.h>
#include <cmath>

#define NPTS 4096
#define NPOINT 204   // int(4096 * 0.05)
#define NPCT 5
#define MAXNS 409    // int(4096 * 0.10)
#define FPS_T 256
#define NGROUP 408   // B * NPOINT
#define NPART (NGROUP * NPCT)
#define MAXSLOT 7    // ceil(409/64)

// fused-launch geometry: 2 FPS blocks + 510 worker blocks = 512 = 2 blocks/CU x 256 CUs
// (R1-proven layout: fused 135.7 us, best measured; R2-R4 restructures reverted)
#define NWORK  510
#define NROUND 4     // 510 * 4 = 2040 = NPART

// shared-memory union layout (bytes)
#define SMEM_BYTES 65600          // fps: float4 pts[4096] (65536) + keys (64)
#define KEYS_OFF   65536
#define WRES_OFF   6544           // grp: gpts float4[409] = 6544
#define WTOT_OFF   20880          //      wres float2[4][7][64] = 14336
#define SPART_OFF  20896
#define SQI_OFF    20912

typedef unsigned long long u64;
typedef float f32x2 __attribute__((ext_vector_type(2)));

struct LossParams {
    int   nsample[NPCT];
    float r2[NPCT];
    float wscale[NPCT];   // (p*100)^2 / (B*NPOINT*NPCT)
    float expect_len;
};

// ---------------- DPP wave64 reductions ------------------------------------
template <int CTRL>
__device__ __forceinline__ int dpp_imax(int v) {
    int t = __builtin_amdgcn_update_dpp(0, v, CTRL, 0xf, 0xf, true);
    return v > t ? v : t;
}
template <int CTRL>
__device__ __forceinline__ int dpp_imin(int v) {
    int t = __builtin_amdgcn_update_dpp(0x7fffffff, v, CTRL, 0xf, 0xf, false);
    return v < t ? v : t;
}
__device__ __forceinline__ int wave_max_i(int v) {
    v = dpp_imax<0x111>(v); v = dpp_imax<0x112>(v);
    v = dpp_imax<0x114>(v); v = dpp_imax<0x118>(v);
    v = dpp_imax<0x142>(v); v = dpp_imax<0x143>(v);
    return __builtin_amdgcn_readlane(v, 63);
}
__device__ __forceinline__ int wave_min_i(int v) {
    v = dpp_imin<0x111>(v); v = dpp_imin<0x112>(v);
    v = dpp_imin<0x114>(v); v = dpp_imin<0x118>(v);
    v = dpp_imin<0x142>(v); v = dpp_imin<0x143>(v);
    return __builtin_amdgcn_readlane(v, 63);
}
template <int CTRL>
__device__ __forceinline__ u64 dpp_u64max(u64 v) {
    int lo = (int)(unsigned)v;
    int hi = (int)(unsigned)(v >> 32);
    unsigned slo = (unsigned)__builtin_amdgcn_update_dpp(0, lo, CTRL, 0xf, 0xf, true);
    unsigned shi = (unsigned)__builtin_amdgcn_update_dpp(0, hi, CTRL, 0xf, 0xf, true);
    u64 o = ((u64)shi << 32) | slo;
    return v > o ? v : o;
}

// ---------------------------------------------------------------------------
// FPS role — R1-proven body (scan argmax, dual DPP chains, keys ping-pong).
// ONE change vs R1: the per-iteration __syncthreads() is replaced by
// {s_waitcnt lgkmcnt(0); raw s_barrier}. __syncthreads' semantics force a
// vmcnt(0) drain, which parks all 4 waves on the t==0 global publish of
// out[it] (~200-500 cy to L2) EVERY iteration. The keys exchange only needs
// LDS visibility (lgkmcnt); the publish store may legally stay in flight
// (distinct address per iter; consumers poll with sleep backoff).
// ---------------------------------------------------------------------------
__device__ void fps_role(const float* __restrict__ pcd,
                         int* __restrict__ fps_idx,
                         char* smem) {
#pragma clang fp contract(off)
    __builtin_amdgcn_s_setprio(3);
    float4* pts = reinterpret_cast<float4*>(smem);          // 64 KB
    u64 (*keys)[4] = reinterpret_cast<u64 (*)[4]>(smem + KEYS_OFF);

    const int b = blockIdx.x;
    const int t = threadIdx.x;
    const int wave = t >> 6, lane = t & 63;
    const float* base = pcd + (size_t)b * NPTS * 3;

    f32x2 X[8], Y[8], Z[8], D[8];
    #pragma unroll
    for (int q = 0; q < 8; ++q) {
        int n0 = (2 * q) * FPS_T + t;
        int n1 = (2 * q + 1) * FPS_T + t;
        float x0 = base[3 * n0 + 0], y0 = base[3 * n0 + 1], z0 = base[3 * n0 + 2];
        float x1 = base[3 * n1 + 0], y1 = base[3 * n1 + 1], z1 = base[3 * n1 + 2];
        pts[n0] = make_float4(x0, y0, z0, 0.0f);
        pts[n1] = make_float4(x1, y1, z1, 0.0f);
        X[q] = (f32x2){x0, x1};
        Y[q] = (f32x2){y0, y1};
        Z[q] = (f32x2){z0, z1};
        D[q] = (f32x2){1e10f, 1e10f};
    }
    int* out = fps_idx + b * NPOINT;
    if (t == 0)
        __hip_atomic_store(&out[0], 0, __ATOMIC_RELAXED, __HIP_MEMORY_SCOPE_AGENT);
    __syncthreads();

    float4 c = pts[0];
    for (int it = 1; it < NPOINT; ++it) {
        f32x2 cxx = (f32x2){c.x, c.x};
        f32x2 cyy = (f32x2){c.y, c.y};
        f32x2 czz = (f32x2){c.z, c.z};
        int bb = -1, bi = 0;
        #pragma unroll
        for (int q = 0; q < 8; ++q) {
            f32x2 dx = X[q] - cxx, dy = Y[q] - cyy, dz = Z[q] - czz;
            f32x2 d  = (dx * dx + dy * dy) + dz * dz;
            f32x2 dd = D[q];
            float d0 = fminf(dd.x, d.x);
            float d1 = fminf(dd.y, d.y);
            D[q] = (f32x2){d0, d1};
            int b0 = __float_as_int(d0);
            int b1 = __float_as_int(d1);
            if (b0 > bb) { bb = b0; bi = (2 * q) * FPS_T + t; }
            if (b1 > bb) { bb = b1; bi = (2 * q + 1) * FPS_T + t; }
        }
        int wmax = wave_max_i(bb);
        int cand = (bb == wmax) ? bi : 0x7fffffff;
        int widx = wave_min_i(cand);
        if (lane == 0)
            keys[it & 1][wave] =
                ((u64)(unsigned)wmax << 32) | (unsigned)~(unsigned)widx;
        // LDS-only barrier: keys write visible after lgkmcnt(0); the out[it]
        // global store is NOT drained here (vs __syncthreads' vmcnt(0)).
        asm volatile("s_waitcnt lgkmcnt(0)" ::: "memory");
        __builtin_amdgcn_s_barrier();
        u64 kv = keys[it & 1][lane & 3];
        kv = dpp_u64max<0x111>(kv);
        kv = dpp_u64max<0x112>(kv);
        unsigned lo3 = (unsigned)__builtin_amdgcn_readlane((int)(unsigned)kv, 3);
        int last = (int)~lo3;
        c = pts[last];
        if (t == 0)
            __hip_atomic_store(&out[it], last, __ATOMIC_RELAXED, __HIP_MEMORY_SCOPE_AGENT);
    }
}

// ---- Phase B worker: K i-slots/lane, j streamed over this wave's quarter ---
template <int K>
__device__ __forceinline__ void phaseB(const float4* __restrict__ gpts,
                                       float2 (*wres)[64],   // [MAXSLOT][64], this wave's slab
                                       int j0, int j1, int lane, int cntB) {
    float4 pi[K];
    float m1[K], m2[K];
    #pragma unroll
    for (int s = 0; s < K; ++s) {
        int idx = s * 64 + lane;
        pi[s] = gpts[idx < cntB ? idx : 0];   // dummy lanes skipped at merge
        m1[s] = 1e30f; m2[s] = 1e30f;
    }
    #pragma unroll 2
    for (int j = j0; j < j1; ++j) {
        float4 a = gpts[j];                   // wave-uniform broadcast read
        #pragma unroll
        for (int s = 0; s < K; ++s) {
            float tt = pi[s].x * a.x;
            tt = fmaf(pi[s].y, a.y, tt);
            tt = fmaf(pi[s].z, a.z, tt);
            float h = fmaf(-2.0f, tt, a.w);   // |a|^2 - 2<pi,a>
            m2[s] = __builtin_amdgcn_fmed3f(m1[s], m2[s], h);
            m1[s] = fminf(m1[s], h);
        }
    }
    #pragma unroll
    for (int s = 0; s < K; ++s) wres[s][lane] = (float2){m1[s], m2[s]};
}

// ---------------------------------------------------------------------------
// Worker role: R1-proven static assignment, tau = w + round*510 (ascending m
// -> tasks unlock progressively while FPS runs). Spin on the fps_idx slot
// itself (agent-scope relaxed load; -1 sentinel) with s_sleep backoff.
// ---------------------------------------------------------------------------
__device__ void worker_role(const float* __restrict__ pcd,
                            int* __restrict__ fps_idx,
                            float* __restrict__ partials,
                            const LossParams& P, char* smem) {
    float4* gpts = reinterpret_cast<float4*>(smem);
    auto wres    = reinterpret_cast<float2 (*)[MAXSLOT][64]>(smem + WRES_OFF);
    int*   s_wtot = reinterpret_cast<int*>(smem + WTOT_OFF);
    float* s_part = reinterpret_cast<float*>(smem + SPART_OFF);
    int*   s_qi   = reinterpret_cast<int*>(smem + SQI_OFF);

    const int w = blockIdx.x - 2;
    const int t = threadIdx.x;
    const int wave = t >> 6, lane = t & 63;

    for (int round = 0; round < NROUND; ++round) {
        const int tau  = w + round * NWORK;          // 0 .. NPART-1, each once
        const int m_   = tau / 10;                   // group row (unlock order)
        const int rem  = tau - m_ * 10;
        const int b    = rem / 5;
        const int pidx = rem - b * 5;

        const int   ns = P.nsample[pidx];
        const float r2 = P.r2[pidx];
        const float* base = pcd + (size_t)b * NPTS * 3;

        if (t == 0) {
            int q;
            while ((q = __hip_atomic_load(&fps_idx[b * NPOINT + m_],
                                          __ATOMIC_RELAXED,
                                          __HIP_MEMORY_SCOPE_AGENT)) < 0)
                __builtin_amdgcn_s_sleep(16);
            s_qi[0] = q;
        }
        __syncthreads();
        const int qi = s_qi[0];
        float qx = base[3 * qi + 0], qy = base[3 * qi + 1], qz = base[3 * qi + 2];

        // ---- Phase A pass 1: ballot the wave's 16 sub-chunks of 64 points ----
        unsigned long long msk[16];
        int lbase[16];
        int run = 0;
        #pragma unroll 4
        for (int s = 0; s < 16; ++s) {
            int n = wave * 1024 + s * 64 + lane;
            float x = base[3 * n + 0];
            float y = base[3 * n + 1];
            float z = base[3 * n + 2];
            float d2;
            {
#pragma clang fp contract(off)
                float dx = qx - x, dy = qy - y, dz = qz - z;
                float aa = dx * dx, bb2 = dy * dy, cc = dz * dz;
                d2 = (aa + bb2) + cc;
            }
            msk[s] = __ballot(d2 < r2);        // strict <, matches reference
            lbase[s] = run;
            run += __popcll(msk[s]);
        }
        if (lane == 0) s_wtot[wave] = run;
        __syncthreads();
        int w0 = s_wtot[0], w1 = s_wtot[1], w2 = s_wtot[2], w3 = s_wtot[3];
        int Bw = (wave > 0 ? w0 : 0) + (wave > 1 ? w1 : 0) + (wave > 2 ? w2 : 0);
        int cnt  = w0 + w1 + w2 + w3;
        int cntB = cnt < ns ? cnt : ns;        // real points kept
        const int npad = ns - cntB;

        // ---- Phase A pass 2: ordered compaction into LDS, w = |p|^2 ----
        #pragma unroll 4
        for (int s = 0; s < 16; ++s) {
            int gb = Bw + lbase[s];            // wave-uniform
            if (gb >= ns) break;
            unsigned long long mk = msk[s];
            bool in = (mk >> lane) & 1ull;
            int pos = gb + __popcll(mk & ((1ull << lane) - 1ull));
            if (in && pos < ns) {
                int n = wave * 1024 + s * 64 + lane;
                float x = base[3 * n], y = base[3 * n + 1], z = base[3 * n + 2];
                float sq = fmaf(x, x, fmaf(y, y, z * z));
                gpts[pos] = make_float4(x, y, z, sq);
            }
        }
        __syncthreads();

        // ---- Phase B: each wave streams its quarter of j ----
        const int quarter = (cntB + 3) >> 2;
        const int j0 = wave * quarter;
        const int j1 = (j0 + quarter) < cntB ? (j0 + quarter) : cntB;
        const int nslot = (cntB + 63) >> 6;    // 1..7
        switch (nslot) {
            case 1: phaseB<1>(gpts, wres[wave], j0, j1, lane, cntB); break;
            case 2: phaseB<2>(gpts, wres[wave], j0, j1, lane, cntB); break;
            case 3: phaseB<3>(gpts, wres[wave], j0, j1, lane, cntB); break;
            case 4: phaseB<4>(gpts, wres[wave], j0, j1, lane, cntB); break;
            case 5: phaseB<5>(gpts, wres[wave], j0, j1, lane, cntB); break;
            case 6: phaseB<6>(gpts, wres[wave], j0, j1, lane, cntB); break;
            default: phaseB<7>(gpts, wres[wave], j0, j1, lane, cntB); break;
        }
        __syncthreads();

        // ---- Merge 4 waves' min2 pairs per i; then sum sqrt ----
        float sum = 0.0f;
        for (int it = t; it < nslot * 64; it += 256) {
            int i = it;                        // = s*64 + l
            if (i < cntB) {
                int s = it >> 6, l = it & 63;
                float2 a  = wres[0][s][l];
                float2 bq = wres[1][s][l];
                float2 cq = wres[2][s][l];
                float2 dq = wres[3][s][l];
                // exact min2 merge: m1=min(a1,b1); m2=min(max(a1,b1),min(a2,b2))
                float e1 = fminf(a.x, bq.x), e2 = fminf(fmaxf(a.x, bq.x), fminf(a.y, bq.y));
                float f1 = fminf(cq.x, dq.x), f2 = fminf(fmaxf(cq.x, dq.x), fminf(cq.y, dq.y));
                float m2v = fminf(fmaxf(e1, f1), fminf(e2, f2));
                float sq = gpts[i].w;
                float d2 = fmaxf(sq + m2v, 0.0f);
                // pads duplicate gpts[0] => i=0's nn is exactly 0 when npad>0
                if (!(i == 0 && npad > 0)) sum += sqrtf(d2);
            }
        }
        #pragma unroll
        for (int off = 32; off; off >>= 1) sum += __shfl_down(sum, off);
        if (lane == 0) s_part[wave] = sum;
        __syncthreads();
        if (t == 0) {
            float tot = s_part[0] + s_part[1] + s_part[2] + s_part[3] + 0.1f * (float)ns;
            float u  = tot / (float)ns;
            float du = u - P.expect_len;
            partials[tau] = du * du / (P.expect_len + 0.1f) * P.wscale[pidx];
        }
        // no extra barrier needed: next round's first shared write (s_wtot)
        // races with nothing still being read from this round.
    }
}

// ---------------------------------------------------------------------------
// Fused kernel: exactly 512 blocks @ 66 KB LDS -> 2 blocks/CU x 256 CU, all
// co-resident by construction (__launch_bounds__(256,2), grid == 2*256), so
// the worker spin cannot deadlock against undispatched FPS blocks.
// ---------------------------------------------------------------------------
__global__ __launch_bounds__(256, 2) void fused_kernel(const float* __restrict__ pcd,
                                                       int* __restrict__ fps_idx,
                                                       float* __restrict__ partials,
                                                       LossParams P) {
    __shared__ __align__(16) char smem[SMEM_BYTES];
    if (blockIdx.x < 2) {
        fps_role(pcd, fps_idx, smem);
    } else {
        worker_role(pcd, fps_idx, partials, P, smem);
    }
}

// ---------------------------------------------------------------------------
// Kernel 3: sum the 2040 per-block partials -> d_out (no atomics anywhere).
// ---------------------------------------------------------------------------
__global__ __launch_bounds__(256) void reduce_kernel(const float* __restrict__ partials,
                                                     float* __restrict__ out) {
    const int t = threadIdx.x;
    __shared__ float sp[4];
    float s = 0.0f;
    for (int i = t; i < NPART; i += 256) s += partials[i];
    #pragma unroll
    for (int off = 32; off; off >>= 1) s += __shfl_down(s, off);
    if ((t & 63) == 0) sp[t >> 6] = s;
    __syncthreads();
    if (t == 0) out[0] = sp[0] + sp[1] + sp[2] + sp[3];
}

extern "C" void kernel_launch(void* const* d_in, const int* in_sizes, int n_in,
                              void* d_out, int out_size, void* d_ws, size_t ws_size,
                              hipStream_t stream) {
    const float* pcd = (const float*)d_in[0];
    const int B = in_sizes[0] / (NPTS * 3);   // = 2
    float* out = (float*)d_out;
    int*   fps = (int*)d_ws;                  // [0, NGROUP) ints
    float* partials = (float*)d_ws + NGROUP;  // [NGROUP, NGROUP+NPART) floats

    // sentinel: -1 means "index m not yet produced" (workspace persists
    // across graph replays, so this must run every invocation)
    hipMemsetAsync(fps, 0xFF, NGROUP * sizeof(int), stream);

    LossParams P;
    const double ps[NPCT] = {0.02, 0.04, 0.06, 0.08, 0.10};
    for (int i = 0; i < NPCT; ++i) {
        P.nsample[i] = (int)(NPTS * ps[i]);
        double r = std::sqrt(ps[i] * 1.0);
        P.r2[i] = (float)(r * r);
        double w = (ps[i] * 100.0) * (ps[i] * 100.0);
        P.wscale[i] = (float)(w / (double)(B * NPOINT * NPCT));
    }
    P.expect_len = (float)std::sqrt(3.14159265358979323846 / (double)NPTS);

    fused_kernel<<<dim3(2 + NWORK), dim3(256), 0, stream>>>(pcd, fps, partials, P);
    reduce_kernel<<<dim3(1), dim3(256), 0, stream>>>(partials, out);
}

// Round 6
// 185.241 us; speedup vs baseline: 1.0524x; 1.0107x over previous
//
#include <hip/hip_runtime.h>
#include <cmath>

#define NPTS 4096
#define NPOINT 204   // int(4096 * 0.05)
#define NPCT 5
#define MAXNS 409    // int(4096 * 0.10)
#define FPS_T 512    // threads per block (8 waves) — R6: was 256 (4 waves)
#define NGROUP 408   // B * NPOINT
#define NPART (NGROUP * NPCT)
#define MAXSLOT 7    // ceil(409/64)
#define NWAVE 8      // waves per block

// fused-launch geometry: 2 FPS blocks + 510 worker blocks = 512 blocks.
// 66 KB LDS + <=128 VGPR (__launch_bounds__(512,4)) -> 2 blocks/CU x 256 CUs,
// all co-resident by construction (same proven layout as R1/R5; only the
// per-block wave count changed 4 -> 8).
#define NWORK  510
#define NROUND 4     // 510 * 4 = 2040 = NPART

// shared-memory union layout (bytes)
#define SMEM_BYTES 65664          // fps: float4 pts[4096] (65536) + keys u64[2][8] (128)
#define KEYS_OFF   65536
#define WRES_OFF   6544           // grp: gpts float4[409] = 6544
#define WTOT_OFF   35216          //      wres float2[8][7][64] = 28672
#define SPART_OFF  35248          //      s_wtot int[8] = 32
#define SQI_OFF    35280          //      s_part float[8] = 32

typedef unsigned long long u64;
typedef float f32x2 __attribute__((ext_vector_type(2)));

struct LossParams {
    int   nsample[NPCT];
    float r2[NPCT];
    float wscale[NPCT];   // (p*100)^2 / (B*NPOINT*NPCT)
    float expect_len;
};

// ---------------- DPP wave64 reductions ------------------------------------
template <int CTRL>
__device__ __forceinline__ int dpp_imax(int v) {
    int t = __builtin_amdgcn_update_dpp(0, v, CTRL, 0xf, 0xf, true);
    return v > t ? v : t;
}
template <int CTRL>
__device__ __forceinline__ int dpp_imin(int v) {
    int t = __builtin_amdgcn_update_dpp(0x7fffffff, v, CTRL, 0xf, 0xf, false);
    return v < t ? v : t;
}
__device__ __forceinline__ int wave_max_i(int v) {
    v = dpp_imax<0x111>(v); v = dpp_imax<0x112>(v);
    v = dpp_imax<0x114>(v); v = dpp_imax<0x118>(v);
    v = dpp_imax<0x142>(v); v = dpp_imax<0x143>(v);
    return __builtin_amdgcn_readlane(v, 63);
}
__device__ __forceinline__ int wave_min_i(int v) {
    v = dpp_imin<0x111>(v); v = dpp_imin<0x112>(v);
    v = dpp_imin<0x114>(v); v = dpp_imin<0x118>(v);
    v = dpp_imin<0x142>(v); v = dpp_imin<0x143>(v);
    return __builtin_amdgcn_readlane(v, 63);
}
template <int CTRL>
__device__ __forceinline__ u64 dpp_u64max(u64 v) {
    int lo = (int)(unsigned)v;
    int hi = (int)(unsigned)(v >> 32);
    unsigned slo = (unsigned)__builtin_amdgcn_update_dpp(0, lo, CTRL, 0xf, 0xf, true);
    unsigned shi = (unsigned)__builtin_amdgcn_update_dpp(0, hi, CTRL, 0xf, 0xf, true);
    u64 o = ((u64)shi << 32) | slo;
    return v > o ? v : o;
}

// ---------------------------------------------------------------------------
// FPS role — same algorithm & tie semantics as the proven 256-thr version,
// now at 512 threads: 8 points/lane (scan depth 8 not 16), 2 waves/SIMD so
// DPP-chain and LDS-read latencies overlap across waves. Cross-wave reduce
// is over 8 wave-keys (3 DPP stages + readlane 7). Keeps the R5 lgkmcnt-only
// barrier (proven neutral, never worse than __syncthreads here).
// Tie rule preserved exactly: per-lane candidates ascend in index (t, 512+t,
// 1024+t, ...) with strict-> keep-earliest; cross-lane/wave ties resolved by
// min index via the ~idx packing.
// ---------------------------------------------------------------------------
__device__ void fps_role(const float* __restrict__ pcd,
                         int* __restrict__ fps_idx,
                         char* smem) {
#pragma clang fp contract(off)
    __builtin_amdgcn_s_setprio(3);
    float4* pts = reinterpret_cast<float4*>(smem);          // 64 KB
    u64 (*keys)[NWAVE] = reinterpret_cast<u64 (*)[NWAVE]>(smem + KEYS_OFF);

    const int b = blockIdx.x;
    const int t = threadIdx.x;
    const int wave = t >> 6, lane = t & 63;
    const float* base = pcd + (size_t)b * NPTS * 3;

    f32x2 X[4], Y[4], Z[4], D[4];
    #pragma unroll
    for (int q = 0; q < 4; ++q) {
        int n0 = (2 * q) * FPS_T + t;
        int n1 = (2 * q + 1) * FPS_T + t;
        float x0 = base[3 * n0 + 0], y0 = base[3 * n0 + 1], z0 = base[3 * n0 + 2];
        float x1 = base[3 * n1 + 0], y1 = base[3 * n1 + 1], z1 = base[3 * n1 + 2];
        pts[n0] = make_float4(x0, y0, z0, 0.0f);
        pts[n1] = make_float4(x1, y1, z1, 0.0f);
        X[q] = (f32x2){x0, x1};
        Y[q] = (f32x2){y0, y1};
        Z[q] = (f32x2){z0, z1};
        D[q] = (f32x2){1e10f, 1e10f};
    }
    int* out = fps_idx + b * NPOINT;
    if (t == 0)
        __hip_atomic_store(&out[0], 0, __ATOMIC_RELAXED, __HIP_MEMORY_SCOPE_AGENT);
    __syncthreads();

    float4 c = pts[0];
    for (int it = 1; it < NPOINT; ++it) {
        f32x2 cxx = (f32x2){c.x, c.x};
        f32x2 cyy = (f32x2){c.y, c.y};
        f32x2 czz = (f32x2){c.z, c.z};
        int bb = -1, bi = 0;
        #pragma unroll
        for (int q = 0; q < 4; ++q) {
            f32x2 dx = X[q] - cxx, dy = Y[q] - cyy, dz = Z[q] - czz;
            f32x2 d  = (dx * dx + dy * dy) + dz * dz;
            f32x2 dd = D[q];
            float d0 = fminf(dd.x, d.x);
            float d1 = fminf(dd.y, d.y);
            D[q] = (f32x2){d0, d1};
            int b0 = __float_as_int(d0);
            int b1 = __float_as_int(d1);
            if (b0 > bb) { bb = b0; bi = (2 * q) * FPS_T + t; }
            if (b1 > bb) { bb = b1; bi = (2 * q + 1) * FPS_T + t; }
        }
        int wmax = wave_max_i(bb);
        int cand = (bb == wmax) ? bi : 0x7fffffff;
        int widx = wave_min_i(cand);
        if (lane == 0)
            keys[it & 1][wave] =
                ((u64)(unsigned)wmax << 32) | (unsigned)~(unsigned)widx;
        // LDS-only barrier (keys visibility needs lgkmcnt, not vmcnt drain)
        asm volatile("s_waitcnt lgkmcnt(0)" ::: "memory");
        __builtin_amdgcn_s_barrier();
        u64 kv = keys[it & 1][lane & 7];     // 8 wave-keys
        kv = dpp_u64max<0x111>(kv);
        kv = dpp_u64max<0x112>(kv);
        kv = dpp_u64max<0x114>(kv);
        unsigned lo7 = (unsigned)__builtin_amdgcn_readlane((int)(unsigned)kv, 7);
        int last = (int)~lo7;
        c = pts[last];
        if (t == 0)
            __hip_atomic_store(&out[it], last, __ATOMIC_RELAXED, __HIP_MEMORY_SCOPE_AGENT);
    }
}

// ---- Phase B worker: K i-slots/lane, j streamed over this wave's eighth ---
// min2 (smallest two incl. self) tracking via med3; exact reference k=2 KNN.
template <int K>
__device__ __forceinline__ void phaseB(const float4* __restrict__ gpts,
                                       float2 (*wres)[64],   // [MAXSLOT][64], this wave's slab
                                       int j0, int j1, int lane, int cntB) {
    float4 pi[K];
    float m1[K], m2[K];
    #pragma unroll
    for (int s = 0; s < K; ++s) {
        int idx = s * 64 + lane;
        pi[s] = gpts[idx < cntB ? idx : 0];   // dummy lanes skipped at merge
        m1[s] = 1e30f; m2[s] = 1e30f;
    }
    #pragma unroll 2
    for (int j = j0; j < j1; ++j) {
        float4 a = gpts[j];                   // wave-uniform broadcast read
        #pragma unroll
        for (int s = 0; s < K; ++s) {
            float tt = pi[s].x * a.x;
            tt = fmaf(pi[s].y, a.y, tt);
            tt = fmaf(pi[s].z, a.z, tt);
            float h = fmaf(-2.0f, tt, a.w);   // |a|^2 - 2<pi,a>
            m2[s] = __builtin_amdgcn_fmed3f(m1[s], m2[s], h);
            m1[s] = fminf(m1[s], h);
        }
    }
    #pragma unroll
    for (int s = 0; s < K; ++s) wres[s][lane] = (float2){m1[s], m2[s]};
}

// exact min2 merge of two (m1,m2) pairs — pure selection, no rounding
__device__ __forceinline__ float2 min2merge(float2 a, float2 b) {
    return (float2){fminf(a.x, b.x),
                    fminf(fmaxf(a.x, b.x), fminf(a.y, b.y))};
}

// ---------------------------------------------------------------------------
// Worker role: R1-proven static assignment, tau = w + round*510 (ascending m
// -> tasks unlock progressively while FPS runs). Per-task math identical;
// only the intra-block decomposition changed: 8 waves x 8 sub-chunks in
// phase A, 8-way j-split in phase B with exact 8-way min2 merge.
// ---------------------------------------------------------------------------
__device__ void worker_role(const float* __restrict__ pcd,
                            int* __restrict__ fps_idx,
                            float* __restrict__ partials,
                            const LossParams& P, char* smem) {
    float4* gpts = reinterpret_cast<float4*>(smem);
    auto wres    = reinterpret_cast<float2 (*)[MAXSLOT][64]>(smem + WRES_OFF);
    int*   s_wtot = reinterpret_cast<int*>(smem + WTOT_OFF);
    float* s_part = reinterpret_cast<float*>(smem + SPART_OFF);
    int*   s_qi   = reinterpret_cast<int*>(smem + SQI_OFF);

    const int w = blockIdx.x - 2;
    const int t = threadIdx.x;
    const int wave = t >> 6, lane = t & 63;

    for (int round = 0; round < NROUND; ++round) {
        const int tau  = w + round * NWORK;          // 0 .. NPART-1, each once
        const int m_   = tau / 10;                   // group row (unlock order)
        const int rem  = tau - m_ * 10;
        const int b    = rem / 5;
        const int pidx = rem - b * 5;

        const int   ns = P.nsample[pidx];
        const float r2 = P.r2[pidx];
        const float* base = pcd + (size_t)b * NPTS * 3;

        if (t == 0) {
            int q;
            while ((q = __hip_atomic_load(&fps_idx[b * NPOINT + m_],
                                          __ATOMIC_RELAXED,
                                          __HIP_MEMORY_SCOPE_AGENT)) < 0)
                __builtin_amdgcn_s_sleep(16);
            s_qi[0] = q;
        }
        __syncthreads();
        const int qi = s_qi[0];
        float qx = base[3 * qi + 0], qy = base[3 * qi + 1], qz = base[3 * qi + 2];

        // ---- Phase A pass 1: ballot the wave's 8 sub-chunks of 64 points ----
        unsigned long long msk[8];
        int lbase[8];
        int run = 0;
        #pragma unroll 4
        for (int s = 0; s < 8; ++s) {
            int n = wave * 512 + s * 64 + lane;
            float x = base[3 * n + 0];
            float y = base[3 * n + 1];
            float z = base[3 * n + 2];
            float d2;
            {
#pragma clang fp contract(off)
                float dx = qx - x, dy = qy - y, dz = qz - z;
                float aa = dx * dx, bb2 = dy * dy, cc = dz * dz;
                d2 = (aa + bb2) + cc;
            }
            msk[s] = __ballot(d2 < r2);        // strict <, matches reference
            lbase[s] = run;
            run += __popcll(msk[s]);
        }
        if (lane == 0) s_wtot[wave] = run;
        __syncthreads();
        int Bw = 0, cnt = 0;
        #pragma unroll
        for (int j = 0; j < NWAVE; ++j) {
            int wj = s_wtot[j];
            cnt += wj;
            if (j < wave) Bw += wj;
        }
        int cntB = cnt < ns ? cnt : ns;        // real points kept
        const int npad = ns - cntB;

        // ---- Phase A pass 2: ordered compaction into LDS, w = |p|^2 ----
        #pragma unroll 4
        for (int s = 0; s < 8; ++s) {
            int gb = Bw + lbase[s];            // wave-uniform
            if (gb >= ns) break;
            unsigned long long mk = msk[s];
            bool in = (mk >> lane) & 1ull;
            int pos = gb + __popcll(mk & ((1ull << lane) - 1ull));
            if (in && pos < ns) {
                int n = wave * 512 + s * 64 + lane;
                float x = base[3 * n], y = base[3 * n + 1], z = base[3 * n + 2];
                float sq = fmaf(x, x, fmaf(y, y, z * z));
                gpts[pos] = make_float4(x, y, z, sq);
            }
        }
        __syncthreads();

        // ---- Phase B: each wave streams its eighth of j ----
        const int eighth = (cntB + 7) >> 3;
        const int j0 = wave * eighth;
        const int j1 = (j0 + eighth) < cntB ? (j0 + eighth) : cntB;
        const int nslot = (cntB + 63) >> 6;    // 1..7
        switch (nslot) {
            case 1: phaseB<1>(gpts, wres[wave], j0, j1, lane, cntB); break;
            case 2: phaseB<2>(gpts, wres[wave], j0, j1, lane, cntB); break;
            case 3: phaseB<3>(gpts, wres[wave], j0, j1, lane, cntB); break;
            case 4: phaseB<4>(gpts, wres[wave], j0, j1, lane, cntB); break;
            case 5: phaseB<5>(gpts, wres[wave], j0, j1, lane, cntB); break;
            case 6: phaseB<6>(gpts, wres[wave], j0, j1, lane, cntB); break;
            default: phaseB<7>(gpts, wres[wave], j0, j1, lane, cntB); break;
        }
        __syncthreads();

        // ---- Merge 8 waves' min2 pairs per i (exact tree); then sum sqrt ----
        float sum = 0.0f;
        for (int it = t; it < nslot * 64; it += FPS_T) {
            int i = it;                        // = s*64 + l
            if (i < cntB) {
                int s = it >> 6, l = it & 63;
                float2 e  = min2merge(wres[0][s][l], wres[1][s][l]);
                float2 f  = min2merge(wres[2][s][l], wres[3][s][l]);
                float2 g  = min2merge(wres[4][s][l], wres[5][s][l]);
                float2 h  = min2merge(wres[6][s][l], wres[7][s][l]);
                float2 ef = min2merge(e, f);
                float2 gh = min2merge(g, h);
                float m2v = fminf(fmaxf(ef.x, gh.x), fminf(ef.y, gh.y));
                float sq = gpts[i].w;
                float d2 = fmaxf(sq + m2v, 0.0f);
                // pads duplicate gpts[0] => i=0's nn is exactly 0 when npad>0
                if (!(i == 0 && npad > 0)) sum += sqrtf(d2);
            }
        }
        #pragma unroll
        for (int off = 32; off; off >>= 1) sum += __shfl_down(sum, off);
        if (lane == 0) s_part[wave] = sum;
        __syncthreads();
        if (t == 0) {
            float tot = 0.0f;
            #pragma unroll
            for (int j = 0; j < NWAVE; ++j) tot += s_part[j];
            tot += 0.1f * (float)ns;
            float u  = tot / (float)ns;
            float du = u - P.expect_len;
            partials[tau] = du * du / (P.expect_len + 0.1f) * P.wscale[pidx];
        }
        // no extra barrier needed: next round's first shared write (s_wtot)
        // races with nothing still being read from this round.
    }
}

// ---------------------------------------------------------------------------
// Fused kernel: 512 blocks x 512 threads @ ~66 KB LDS, <=128 VGPR
// (__launch_bounds__(512,4)) -> 2 blocks/CU x 256 CU, all co-resident, so
// the worker spin cannot deadlock against undispatched FPS blocks.
// ---------------------------------------------------------------------------
__global__ __launch_bounds__(FPS_T, 4) void fused_kernel(const float* __restrict__ pcd,
                                                         int* __restrict__ fps_idx,
                                                         float* __restrict__ partials,
                                                         LossParams P) {
    __shared__ __align__(16) char smem[SMEM_BYTES];
    if (blockIdx.x < 2) {
        fps_role(pcd, fps_idx, smem);
    } else {
        worker_role(pcd, fps_idx, partials, P, smem);
    }
}

// ---------------------------------------------------------------------------
// Kernel 3: sum the 2040 per-block partials -> d_out (no atomics anywhere).
// ---------------------------------------------------------------------------
__global__ __launch_bounds__(256) void reduce_kernel(const float* __restrict__ partials,
                                                     float* __restrict__ out) {
    const int t = threadIdx.x;
    __shared__ float sp[4];
    float s = 0.0f;
    for (int i = t; i < NPART; i += 256) s += partials[i];
    #pragma unroll
    for (int off = 32; off; off >>= 1) s += __shfl_down(s, off);
    if ((t & 63) == 0) sp[t >> 6] = s;
    __syncthreads();
    if (t == 0) out[0] = sp[0] + sp[1] + sp[2] + sp[3];
}

extern "C" void kernel_launch(void* const* d_in, const int* in_sizes, int n_in,
                              void* d_out, int out_size, void* d_ws, size_t ws_size,
                              hipStream_t stream) {
    const float* pcd = (const float*)d_in[0];
    const int B = in_sizes[0] / (NPTS * 3);   // = 2
    float* out = (float*)d_out;
    int*   fps = (int*)d_ws;                  // [0, NGROUP) ints
    float* partials = (float*)d_ws + NGROUP;  // [NGROUP, NGROUP+NPART) floats

    // sentinel: -1 means "index m not yet produced" (workspace persists
    // across graph replays, so this must run every invocation)
    hipMemsetAsync(fps, 0xFF, NGROUP * sizeof(int), stream);

    LossParams P;
    const double ps[NPCT] = {0.02, 0.04, 0.06, 0.08, 0.10};
    for (int i = 0; i < NPCT; ++i) {
        P.nsample[i] = (int)(NPTS * ps[i]);
        double r = std::sqrt(ps[i] * 1.0);
        P.r2[i] = (float)(r * r);
        double w = (ps[i] * 100.0) * (ps[i] * 100.0);
        P.wscale[i] = (float)(w / (double)(B * NPOINT * NPCT));
    }
    P.expect_len = (float)std::sqrt(3.14159265358979323846 / (double)NPTS);

    fused_kernel<<<dim3(2 + NWORK), dim3(FPS_T), 0, stream>>>(pcd, fps, partials, P);
    reduce_kernel<<<dim3(1), dim3(256), 0, stream>>>(partials, out);
}